// Round 13
// baseline (593.904 us; speedup 1.0000x reference)
//
#include <hip/hip_runtime.h>
#include <hip/hip_bf16.h>

#define UU 60000
#define II 90000
#define DD 64
#define NN 150000
#define NNZC 1000000
#define NTOT 7000000
#define MTOT 870000           // 5*NN + 2*UU
#define ROW_S0 750000         // start of social rows (5*NN)
#define NBR 733               // rating buckets (1024 rows each)
#define NBCK 1046             // + 313 social buckets (384 rows each)
#define CAPE 8192             // staging slots per bucket / phaseB LDS sort capacity
#define ACH 16384             // edges per partition block
#define GRID_A 428            // ceil(NTOT/ACH)
#define ABLK 1024             // partition block size (16 edges/thread)

struct SpmmJob {
    int mode;           // 0: rating L1, 1: rating L2, 2: social L1, 3: social L2
    int rowBase;
    int nRows;
    const uint2* tblB;  // bf16x4 gather table [*][16]
    const uint2* selfB;
    uint2* outB;
    float4* outF;
    float* wOut;
};

struct CvtJob {
    const float* lo;
    const float* hi;
    uint2* dst;
    int nRows;
    int split;
};

__device__ __forceinline__ int wave_incl_scan(int x) {
    int lane = threadIdx.x & 63;
#pragma unroll
    for (int d = 1; d < 64; d <<= 1) {
        int y = __shfl_up(x, d, 64);
        if (lane >= d) x += y;
    }
    return x;
}

__device__ int block_incl_scan(int x, int* lds) {
    int wid = threadIdx.x >> 6, lane = threadIdx.x & 63;
    int ws_ = wave_incl_scan(x);
    if (lane == 63) lds[wid] = ws_;
    __syncthreads();
    int off = 0;
    for (int w = 0; w < wid; ++w) off += lds[w];
    __syncthreads();
    return ws_ + off;
}

__device__ __forceinline__ float2 unpack_bf16x2(unsigned p) {
    float2 r;
    r.x = __uint_as_float(p << 16);
    r.y = __uint_as_float(p & 0xffff0000u);
    return r;
}

__device__ __forceinline__ unsigned pack_bf16x2(float a, float b) {
    __hip_bfloat162 h = __float22bfloat162_rn(make_float2(a, b));
    return *(unsigned*)&h;
}

__device__ __forceinline__ uint2 pack4(float4 m) {
    return make_uint2(pack_bf16x2(m.x, m.y), pack_bf16x2(m.z, m.w));
}

__device__ __forceinline__ float4 unpack4(uint2 p) {
    float2 a = unpack_bf16x2(p.x), b = unpack_bf16x2(p.y);
    return make_float4(a.x, a.y, b.x, b.y);
}

__device__ __forceinline__ int bid_of(int grow) {
    return (grow < ROW_S0) ? (grow >> 10) : NBR + (grow - ROW_S0) / 384;
}

// f32 table(s) -> bf16x4 table, grid-stride over nRows*16 elements
__device__ __forceinline__ void cvt_body(int blk, int nblks, const CvtJob& cv) {
    int total = cv.nRows * 16;
    int stride = nblks * (int)blockDim.x;
    for (int i = blk * (int)blockDim.x + (int)threadIdx.x; i < total; i += stride) {
        int row = i >> 4, h = i & 15;
        const float* src = (row < cv.split) ? (cv.lo + (size_t)row * DD)
                                            : (cv.hi + (size_t)(row - cv.split) * DD);
        float4 x = *(const float4*)(src + 4 * h);
        cv.dst[i] = pack4(x);
    }
}

// Single-pass staged build with register-cached rows:
// pass 1 decodes rows fully -> gw[16] in VGPRs, counts buckets;
// pass 2 loads only cols/vals, ranks via LDS atomic, staged write.
// Pure scatter kernel: no streaming co-tenants (R11 lesson).
__global__ __launch_bounds__(ABLK) void pa_single_kernel(
        const int* __restrict__ rR, const int* __restrict__ rC, const float* __restrict__ rV,
        const int* __restrict__ fR, const int* __restrict__ fC, const float* __restrict__ fV,
        const int* __restrict__ gR, const int* __restrict__ gC, const float* __restrict__ gV,
        int* __restrict__ bucketCur, uint2* __restrict__ ecv) {
    __shared__ int lcnt[NBCK];
    __shared__ int lbase[NBCK];
    int k = blockIdx.x;
    int cbase = k * ACH;
    int eEnd = min(cbase + ACH, NTOT);
    for (int b = threadIdx.x; b < NBCK; b += ABLK) lcnt[b] = 0;
    __syncthreads();
    // pass 1: decode rows (cached in registers), count buckets
    int gw[16];
#pragma unroll
    for (int t = 0; t < 16; ++t) {
        int e = cbase + t * ABLK + (int)threadIdx.x;
        bool v = e < eEnd;
        int ec = v ? e : cbase;
        int grow;
        if (ec < 5 * NNZC) grow = (ec / NNZC) * NN + rR[ec];
        else if (ec < 6 * NNZC) grow = ROW_S0 + fR[ec - 5 * NNZC];
        else grow = ROW_S0 + UU + gR[ec - 6 * NNZC];
        gw[t] = v ? grow : -1;
    }
#pragma unroll
    for (int t = 0; t < 16; ++t)
        if (gw[t] >= 0) atomicAdd(&lcnt[bid_of(gw[t])], 1);
    __syncthreads();
    // reserve staging space per bucket
    for (int b = threadIdx.x; b < NBCK; b += ABLK) {
        int n = lcnt[b];
        lbase[b] = n ? atomicAdd(&bucketCur[b], n) : 0;
    }
    __syncthreads();
    for (int b = threadIdx.x; b < NBCK; b += ABLK) lcnt[b] = 0;
    __syncthreads();
    // pass 2: cols/vals loads (4-wide MLP) + LDS rank + staged write
#pragma unroll
    for (int t0 = 0; t0 < 16; t0 += 4) {
        int cc[4]; float vv[4];
#pragma unroll
        for (int u = 0; u < 4; ++u) {
            int t = t0 + u;
            int e = cbase + t * ABLK + (int)threadIdx.x;
            int ec = (gw[t] >= 0) ? e : cbase;
            if (ec < 5 * NNZC) { cc[u] = rC[ec]; vv[u] = rV[ec]; }
            else if (ec < 6 * NNZC) { int kk = ec - 5 * NNZC; cc[u] = fC[kk]; vv[u] = fV[kk]; }
            else { int kk = ec - 6 * NNZC; cc[u] = gC[kk]; vv[u] = gV[kk]; }
        }
        int rk[4], bb[4];
#pragma unroll
        for (int u = 0; u < 4; ++u) {
            int t = t0 + u;
            bb[u] = (gw[t] >= 0) ? bid_of(gw[t]) : 0;
            rk[u] = (gw[t] >= 0) ? atomicAdd(&lcnt[bb[u]], 1) : CAPE;
        }
#pragma unroll
        for (int u = 0; u < 4; ++u) {
            int t = t0 + u;
            if (gw[t] < 0) continue;
            int off = lbase[bb[u]] + rk[u];
            if (off >= CAPE) continue;  // +16 sigma guard
            int lrow = (gw[t] < ROW_S0) ? (gw[t] & 1023) : ((gw[t] - ROW_S0) % 384);
            ecv[(size_t)bb[u] * CAPE + off] =
                make_uint2(((unsigned)lrow << 18) | (unsigned)cc[u], __float_as_uint(vv[u]));
        }
    }
}

// block 0: exclusive scan -> bStart + sentinels; blocks [1,1+cvB): cvt; block 1+cvB: att_vec
__global__ __launch_bounds__(256) void bscan_kernel(const int* __restrict__ bucketCur,
                                                    int* __restrict__ bStart,
                                                    int* __restrict__ rowptr,
                                                    CvtJob cv, int cvB,
                                                    const float* __restrict__ au,
                                                    const float* __restrict__ Mu,
                                                    const float* __restrict__ ai,
                                                    const float* __restrict__ Mi,
                                                    const float* __restrict__ as_,
                                                    const float* __restrict__ Ms,
                                                    float* __restrict__ vvec) {
    if ((int)blockIdx.x == 1 + cvB) {
        // att_vec: vvec = {Mu^T au, Mi^T ai, Ms^T as}
        int d = threadIdx.x;
        if (d < DD) {
            float su = 0.f, si = 0.f, ss = 0.f;
            for (int e = 0; e < DD; ++e) {
                su += au[e] * Mu[e * DD + d];
                si += ai[e] * Mi[e * DD + d];
                ss += as_[e] * Ms[e * DD + d];
            }
            vvec[d] = su;
            vvec[DD + d] = si;
            vvec[2 * DD + d] = ss;
        }
        return;
    }
    if (blockIdx.x > 0) {
        cvt_body(blockIdx.x - 1, cvB, cv);
        return;
    }
    __shared__ int lds8[8];
    __shared__ int sOff;
    if (threadIdx.x == 0) sOff = 0;
    __syncthreads();
    for (int base = 0; base < NBCK; base += 256) {
        int i = base + threadIdx.x;
        int v = (i < NBCK) ? min(bucketCur[i], CAPE) : 0;
        int incl = block_incl_scan(v, lds8);
        if (i < NBCK) bStart[i] = sOff + incl - v;
        __syncthreads();
        if (threadIdx.x == 255) sOff += incl;
        __syncthreads();
    }
    if (threadIdx.x == 0) { bStart[NBCK] = sOff; rowptr[MTOT] = sOff; }
}

// per-bucket LDS permutation sort: staging (b*CAPE) -> compact row-sorted edata;
// emits rowptr (+ folded cvt tail)
__global__ __launch_bounds__(256) void phaseB_kernel(const int* __restrict__ bStart,
                                                     const int* __restrict__ bucketCur,
                                                     int* __restrict__ rowptr,
                                                     const uint2* __restrict__ ecv,
                                                     uint2* __restrict__ edata,
                                                     CvtJob cv, int cvB) {
    if ((int)blockIdx.x >= NBCK) {
        cvt_body(blockIdx.x - NBCK, cvB, cv);
        return;
    }
    __shared__ unsigned short perm[CAPE];  // 16 KB
    __shared__ int off[1024];
    __shared__ int lds8[8];
    int b = blockIdx.x;
    int firstRow = (b < NBR) ? (b << 10) : ROW_S0 + (b - NBR) * 384;
    int rowEnd = (b < NBR) ? min((b + 1) << 10, ROW_S0)
                           : min(ROW_S0 + (b - NBR + 1) * 384, MTOT);
    int nRows = rowEnd - firstRow;
    size_t src = (size_t)b * CAPE;
    int dst = bStart[b];
    int count = min(bucketCur[b], CAPE);
    for (int i = threadIdx.x; i < nRows; i += 256) off[i] = 0;
    __syncthreads();
    for (int i = threadIdx.x; i < count; i += 256)
        atomicAdd(&off[ecv[src + i].x >> 18], 1);
    __syncthreads();
    int base4 = threadIdx.x * 4;
    int v4[4], s = 0;
#pragma unroll
    for (int kk = 0; kk < 4; ++kk) {
        int i = base4 + kk;
        v4[kk] = (i < nRows) ? off[i] : 0;
        s += v4[kk];
    }
    int incl = block_incl_scan(s, lds8);
    int run = incl - s;
#pragma unroll
    for (int kk = 0; kk < 4; ++kk) {
        int i = base4 + kk;
        if (i < nRows) { rowptr[firstRow + i] = dst + run; off[i] = run; }
        run += v4[kk];
    }
    __syncthreads();
    for (int i = threadIdx.x; i < count; i += 256) {
        int pos = atomicAdd(&off[ecv[src + i].x >> 18], 1);
        perm[pos] = (unsigned short)i;
    }
    __syncthreads();
    for (int i = threadIdx.x; i < count; i += 256) {
        uint2 e = ecv[src + perm[i]];
        edata[dst + i] = make_uint2(e.x & 0x3FFFFu, e.y);
    }
}

// 16 lanes/row, 4 rows/wave, 8-edge MLP batches; ALL gathers bf16x4 from tblB.
template <int MODE>
__device__ __forceinline__ void spmm_body(int blk, const SpmmJob& j,
                                          const int* __restrict__ rowptr,
                                          const uint2* __restrict__ edata,
                                          const float* __restrict__ vvec) {
    int lane = threadIdx.x & 63;
    int l16 = lane & 15;
    int grpBase = lane & 48;
    int wid = blk * (int)(blockDim.x >> 6) + (threadIdx.x >> 6);
    int row = wid * 4 + (lane >> 4);
    bool active = row < j.nRows;
    int g = j.rowBase + row;
    int start = active ? rowptr[g] : 0;
    int end = active ? rowptr[g + 1] : 0;
    float4 acc = make_float4(0.f, 0.f, 0.f, 0.f);
    for (int j0 = start; j0 < end; j0 += 16) {
        uint2 md = make_uint2(0u, 0u);
        if (j0 + l16 < end) md = edata[j0 + l16];
        int cnt = min(end - j0, 16);
        for (int js = 0; js < cnt; js += 8) {
            int cc[8]; float vv[8]; float4 xv[8];
#pragma unroll
            for (int u = 0; u < 8; ++u) {
                int jj = js + u;
                int sl = grpBase + ((jj < cnt) ? jj : 0);
                cc[u] = __shfl((int)md.x, sl, 64);
                float v = __uint_as_float((unsigned)__shfl((int)md.y, sl, 64));
                vv[u] = (jj < cnt) ? v : 0.f;
            }
#pragma unroll
            for (int u = 0; u < 8; ++u)
                xv[u] = unpack4(j.tblB[(size_t)cc[u] * 16 + l16]);
#pragma unroll
            for (int u = 0; u < 8; ++u) {
                acc.x += vv[u] * xv[u].x; acc.y += vv[u] * xv[u].y;
                acc.z += vv[u] * xv[u].z; acc.w += vv[u] * xv[u].w;
            }
        }
    }
    if (!active) return;
    size_t ro = (size_t)row * 16 + l16;
    if (MODE == 0) {
        j.outB[ro] = pack4(acc);
    } else if (MODE == 1) {
        float4 sv = unpack4(j.selfB[ro]);
        float4 m = make_float4(0.5f * (acc.x + sv.x), 0.5f * (acc.y + sv.y),
                               0.5f * (acc.z + sv.z), 0.5f * (acc.w + sv.w));
        j.outB[ro] = pack4(m);
        const float* vv = (row < UU) ? vvec : (vvec + DD);
        float4 vw = *(const float4*)(vv + 4 * l16);
        float p = m.x * vw.x + m.y * vw.y + m.z * vw.z + m.w * vw.w;
        p += __shfl_xor(p, 1, 64); p += __shfl_xor(p, 2, 64);
        p += __shfl_xor(p, 4, 64); p += __shfl_xor(p, 8, 64);
        if (l16 == 0) j.wOut[row] = tanhf(p);
    } else if (MODE == 2) {
        float n2 = acc.x * acc.x + acc.y * acc.y + acc.z * acc.z + acc.w * acc.w;
        n2 += __shfl_xor(n2, 1, 64); n2 += __shfl_xor(n2, 2, 64);
        n2 += __shfl_xor(n2, 4, 64); n2 += __shfl_xor(n2, 8, 64);
        float inv = 1.f / fmaxf(sqrtf(n2), 1e-12f);
        j.outB[ro] = pack4(make_float4(acc.x * inv, acc.y * inv, acc.z * inv, acc.w * inv));
    } else {
        float n2 = acc.x * acc.x + acc.y * acc.y + acc.z * acc.z + acc.w * acc.w;
        n2 += __shfl_xor(n2, 1, 64); n2 += __shfl_xor(n2, 2, 64);
        n2 += __shfl_xor(n2, 4, 64); n2 += __shfl_xor(n2, 8, 64);
        float inv = 1.f / fmaxf(sqrtf(n2), 1e-12f);
        float4 sv = unpack4(j.selfB[ro]);
        j.outF[ro] = make_float4(0.5f * (sv.x + acc.x * inv), 0.5f * (sv.y + acc.y * inv),
                                 0.5f * (sv.z + acc.z * inv), 0.5f * (sv.w + acc.w * inv));
    }
}

__device__ __forceinline__ void spmm_run(const SpmmJob& j, int blk,
                                         const int* __restrict__ rowptr,
                                         const uint2* __restrict__ edata,
                                         const float* __restrict__ vvec) {
    switch (j.mode) {
        case 0: spmm_body<0>(blk, j, rowptr, edata, vvec); break;
        case 1: spmm_body<1>(blk, j, rowptr, edata, vvec); break;
        case 2: spmm_body<2>(blk, j, rowptr, edata, vvec); break;
        default: spmm_body<3>(blk, j, rowptr, edata, vvec); break;
    }
}

// up to two spmm jobs + folded cvt tail
__global__ __launch_bounds__(256) void fused_kernel(SpmmJob a, int aB, SpmmJob b, int bB,
                                                    CvtJob cv, int cvB,
                                                    const int* __restrict__ rowptr,
                                                    const uint2* __restrict__ edata,
                                                    const float* __restrict__ vvec) {
    int bx = blockIdx.x;
    if (bx < aB) { spmm_run(a, bx, rowptr, edata, vvec); return; }
    bx -= aB;
    if (bx < bB) { spmm_run(b, bx, rowptr, edata, vvec); return; }
    cvt_body(bx - bB, cvB, cv);
}

// blocks [0,nMix): user+item 5-channel softmax mix; then two social-L1 spmm jobs
__global__ __launch_bounds__(256) void mix_social_kernel(
        const __hip_bfloat16* __restrict__ chanEmb, const float* __restrict__ w,
        float* __restrict__ oUS, float* __restrict__ oIS,
        float* __restrict__ mixedRU, float* __restrict__ oMI, int nMix,
        SpmmJob s0, int s0B, SpmmJob s1,
        const int* __restrict__ rowptr, const uint2* __restrict__ edata,
        const float* __restrict__ vvec) {
    if ((int)blockIdx.x >= nMix) {
        int r = blockIdx.x - nMix;
        if (r < s0B) spmm_body<2>(r, s0, rowptr, edata, vvec);
        else spmm_body<2>(r - s0B, s1, rowptr, edata, vvec);
        return;
    }
    int lane = threadIdx.x & 63;
    int n = blockIdx.x * 4 + (threadIdx.x >> 6);
    if (n >= NN) return;
    float sw[5];
    float mx = -2.0f;
#pragma unroll
    for (int c = 0; c < 5; ++c) {
        sw[c] = w[(size_t)c * NN + n];
        mx = fmaxf(mx, sw[c]);
    }
    float sum = 0.f;
#pragma unroll
    for (int c = 0; c < 5; ++c) {
        sw[c] = expf(sw[c] - mx);
        sum += sw[c];
    }
    float inv = 1.0f / sum;
    float acc = 0.f;
#pragma unroll
    for (int c = 0; c < 5; ++c) {
        sw[c] *= inv;
        acc += sw[c] * __bfloat162float(chanEmb[((size_t)c * NN + n) * DD + lane]);
    }
    if (n < UU) {
#pragma unroll
        for (int c = 0; c < 5; ++c)
            if (lane == c) oUS[(size_t)c * UU + n] = sw[c];
        mixedRU[(size_t)n * DD + lane] = acc;
    } else {
        int m = n - UU;
#pragma unroll
        for (int c = 0; c < 5; ++c)
            if (lane == c) oIS[(size_t)c * II + m] = sw[c];
        oMI[(size_t)m * DD + lane] = acc;
    }
}

// social 2-channel softmax fuse + adaptive final combine
__global__ void social_mix_final_kernel(const float* __restrict__ e0, const float* __restrict__ e1,
                                        const float* __restrict__ vs,
                                        const float* __restrict__ mixedRU,
                                        const float* __restrict__ adaptive,
                                        float* __restrict__ scoresOut,
                                        float* __restrict__ outMU) {
    int lane = threadIdx.x & 63;
    int n = blockIdx.x * (blockDim.x >> 6) + (threadIdx.x >> 6);
    if (n >= UU) return;
    size_t idx = (size_t)n * DD + lane;
    float a = e0[idx];
    float b = e1[idx];
    float v = vs[lane];
    float pa = a * v, pb = b * v;
    float mru = mixedRU[idx];
#pragma unroll
    for (int m = 32; m >= 1; m >>= 1) { pa += __shfl_xor(pa, m, 64); pb += __shfl_xor(pb, m, 64); }
    float w0 = tanhf(pa);
    float w1 = tanhf(pb);
    float mx = fmaxf(w0, w1);
    float x0 = expf(w0 - mx);
    float x1 = expf(w1 - mx);
    float invs = 1.0f / (x0 + x1);
    float s0 = x0 * invs;
    float s1 = x1 * invs;
    if (lane == 0) {
        scoresOut[n] = s0;
        scoresOut[UU + n] = s1;
    }
    float ms = s0 * a + s1 * b;
    float nm = mru * ms, na2 = mru * mru, nb2 = ms * ms;
#pragma unroll
    for (int m = 32; m >= 1; m >>= 1) {
        nm += __shfl_xor(nm, m, 64); na2 += __shfl_xor(na2, m, 64); nb2 += __shfl_xor(nb2, m, 64);
    }
    float denom = fmaxf(sqrtf(na2), 1e-8f) * fmaxf(sqrtf(nb2), 1e-8f);
    float sim = nm / denom;
    float rate = 1.0f / (2.0f + fmaxf(sim, 0.f) * adaptive[n]);
    outMU[idx] = mru + ms * rate;
}

extern "C" void kernel_launch(void* const* d_in, const int* in_sizes, int n_in,
                              void* d_out, int out_size, void* d_ws, size_t ws_size,
                              hipStream_t stream) {
    const int* r_rows = (const int*)d_in[0];
    const int* r_cols = (const int*)d_in[1];
    const float* r_vals = (const float*)d_in[2];
    const int* f_rows = (const int*)d_in[3];
    const int* f_cols = (const int*)d_in[4];
    const float* f_vals = (const float*)d_in[5];
    const int* g_rows = (const int*)d_in[6];
    const int* g_cols = (const int*)d_in[7];
    const float* g_vals = (const float*)d_in[8];
    const float* rue = (const float*)d_in[9];
    const float* rie = (const float*)d_in[10];
    const float* femb = (const float*)d_in[11];
    const float* gemb = (const float*)d_in[12];
    const float* uaw = (const float*)d_in[13];
    const float* uamw = (const float*)d_in[14];
    const float* iaw = (const float*)d_in[15];
    const float* iamw = (const float*)d_in[16];
    const float* saw = (const float*)d_in[17];
    const float* samw = (const float*)d_in[18];
    const float* adapt = (const float*)d_in[19];

    // ws layout (float units) — total 55,944,320 floats = 223.8 MB (< 233.4 proven)
    float* ws = (float*)d_ws;
    int* rowptr = (int*)ws;                              // 870,016
    int* bStart = rowptr + 870016;                       // 2,048
    int* bucketCur = bStart + 2048;                      // 2,048 -> meta ends @874,112
    float* ED   = ws + 874112;                           // 14,000,000 (edata)
    float* R1   = ED + 14000000;                         // 11,520,000
    float* CM   = R1 + 11520000;                         // 24,000,000
    float* tbl0F= CM + 24000000;                         // 4,800,000
    float* wrat = tbl0F + 4800000;                       // 750,016
    float* vvec = wrat + 750016;                         // 192

    uint2* edata = (uint2*)ED;
    // R1: AtmpB ping-pong during rating; mixedRU/socM after
    uint2* AtmpB0 = (uint2*)R1;                          // NN*16 uint2
    uint2* AtmpB1 = AtmpB0 + (size_t)NN * 16;
    float* mixedRU = R1;                                 // UU*64 f32 (after rating)
    float* socM0 = R1 + 3840000;
    float* socM1 = R1 + 7680000;
    // CM: ecv staging during build; chanMean slices after; tbl1 at slice-4 space
    uint2* ecv = (uint2*)CM;
    __hip_bfloat16* chanMean = (__hip_bfloat16*)CM;      // 5*NN*64 bf16
    uint2* tbl1 = (uint2*)(CM + 19200000);               // chanMean slice-4 space
    // tbl0 region; socB aliases after last rating L1
    uint2* tbl0 = (uint2*)tbl0F;
    uint2* socB0 = (uint2*)tbl0F;                        // UU*16 uint2
    uint2* socB1 = socB0 + (size_t)UU * 16;

    float* out = (float*)d_out;
    float* oUS = out;
    float* oIS = oUS + (size_t)5 * UU;
    float* oSS = oIS + (size_t)5 * II;
    float* oMU = oSS + (size_t)2 * UU;
    float* oMI = oMU + (size_t)UU * DD;
    // socL1B scratch lives in the oMU output region (exactly UU*DD floats;
    // dead until social_mix_final overwrites it)
    uint2* socL1B0 = (uint2*)oMU;                        // UU*16 uint2
    uint2* socL1B1 = socL1B0 + (size_t)UU * 16;

    const dim3 blk(256);
    const dim3 blkA(ABLK);
    const int gridN4 = (NN + 15) / 16;    // 9375
    const int gridU4 = (UU + 15) / 16;    // 3750
    const int gridMix = (NN + 3) / 4;     // 37500
    const int gridFin = (UU + 3) / 4;
    const int CVB = 2048;                 // cvt tail blocks

    uint2* tblOf[2] = {tbl0, tbl1};
    auto cvtRating = [&](int c) {
        CvtJob cv{};
        cv.lo = rue + (size_t)c * UU * DD;
        cv.hi = rie + (size_t)c * II * DD;
        cv.dst = tblOf[c & 1];
        cv.nRows = NN; cv.split = UU;
        return cv;
    };
    CvtJob cvNone{};
    cvNone.lo = rue; cvNone.hi = rie; cvNone.dst = tbl0; cvNone.nRows = 0; cvNone.split = UU;

    // ---- build row-sorted CSR: single-pass staged scatter ----
    hipMemsetAsync(bucketCur, 0, NBCK * sizeof(int), stream);
    pa_single_kernel<<<GRID_A, blkA, 0, stream>>>(r_rows, r_cols, r_vals,
                                                  f_rows, f_cols, f_vals,
                                                  g_rows, g_cols, g_vals,
                                                  bucketCur, ecv);
    bscan_kernel<<<2 + CVB, blk, 0, stream>>>(bucketCur, bStart, rowptr,
                                              cvtRating(0), CVB,
                                              uaw, uamw, iaw, iamw, saw, samw, vvec);
    phaseB_kernel<<<NBCK + CVB, blk, 0, stream>>>(bStart, bucketCur, rowptr, ecv, edata,
                                                  cvtRating(1), CVB);

    // ---- rating channels: L1(c) || L2(c-1), cvt(c+1) folded ----
    auto jobL1 = [&](int c) {
        SpmmJob j{};
        j.mode = 0; j.rowBase = c * NN; j.nRows = NN;
        j.tblB = tblOf[c & 1];
        j.outB = (c & 1) ? AtmpB1 : AtmpB0;
        return j;
    };
    auto jobL2 = [&](int c) {
        SpmmJob j{};
        j.mode = 1; j.rowBase = c * NN; j.nRows = NN;
        j.tblB = (c & 1) ? AtmpB1 : AtmpB0;
        j.selfB = j.tblB;
        j.outB = (uint2*)(chanMean + (size_t)c * NN * DD);
        j.wOut = wrat + (size_t)c * NN;
        return j;
    };
    SpmmJob jNone{}; jNone.mode = 0; jNone.nRows = 0; jNone.tblB = tbl0; jNone.outB = AtmpB0;

    // L1(0) only
    fused_kernel<<<gridN4, blk, 0, stream>>>(jobL1(0), gridN4, jNone, 0, cvNone, 0,
                                             rowptr, edata, vvec);
    // dual launches + cvt(c+1)
    for (int c = 1; c <= 3; ++c)
        fused_kernel<<<2 * gridN4 + CVB, blk, 0, stream>>>(
            jobL1(c), gridN4, jobL2(c - 1), gridN4, cvtRating(c + 1), CVB,
            rowptr, edata, vvec);
    // dual(4), no cvt
    fused_kernel<<<2 * gridN4, blk, 0, stream>>>(jobL1(4), gridN4, jobL2(3), gridN4,
                                                 cvNone, 0, rowptr, edata, vvec);
    // L2(4) + social table cvt (femb->socB0, gemb->socB1 contiguous)
    CvtJob cvSoc{};
    cvSoc.lo = femb; cvSoc.hi = gemb; cvSoc.dst = socB0; cvSoc.nRows = 2 * UU; cvSoc.split = UU;
    fused_kernel<<<gridN4 + CVB, blk, 0, stream>>>(jobL2(4), gridN4, jNone, 0, cvSoc, CVB,
                                                   rowptr, edata, vvec);

    // ---- attention fuse (rating) || social L1 (socL1B scratch in d_out oMU region) ----
    SpmmJob sf1{}; sf1.mode = 2; sf1.rowBase = ROW_S0; sf1.nRows = UU;
    sf1.tblB = socB0; sf1.outB = socL1B0;
    SpmmJob sg1{}; sg1.mode = 2; sg1.rowBase = ROW_S0 + UU; sg1.nRows = UU;
    sg1.tblB = socB1; sg1.outB = socL1B1;
    mix_social_kernel<<<gridMix + 2 * gridU4, blk, 0, stream>>>(
        chanMean, wrat, oUS, oIS, mixedRU, oMI, gridMix,
        sf1, gridU4, sg1, rowptr, edata, vvec);

    // ---- social L2 ----
    SpmmJob sf2{}; sf2.mode = 3; sf2.rowBase = ROW_S0; sf2.nRows = UU;
    sf2.tblB = socL1B0; sf2.selfB = socL1B0; sf2.outF = (float4*)socM0;
    SpmmJob sg2{}; sg2.mode = 3; sg2.rowBase = ROW_S0 + UU; sg2.nRows = UU;
    sg2.tblB = socL1B1; sg2.selfB = socL1B1; sg2.outF = (float4*)socM1;
    fused_kernel<<<2 * gridU4, blk, 0, stream>>>(sf2, gridU4, sg2, gridU4, cvNone, 0,
                                                 rowptr, edata, vvec);

    // ---- social fuse + adaptive combine (overwrites oMU scratch with real output) ----
    social_mix_final_kernel<<<gridFin, blk, 0, stream>>>(socM0, socM1, vvec + 2 * DD,
                                                         mixedRU, adapt, oSS, oMU);
}

// Round 14
// 561.726 us; speedup vs baseline: 1.0573x; 1.0573x over previous
//
#include <hip/hip_runtime.h>
#include <hip/hip_bf16.h>

#define UU 60000
#define II 90000
#define DD 64
#define NN 150000
#define NNZC 1000000
#define NTOT 7000000
#define MTOT 870000           // 5*NN + 2*UU
#define ROW_S0 750000         // start of social rows (5*NN)
#define NBR 733               // rating buckets (1024 rows each)
#define NBCK 1046             // + 313 social buckets (384 rows each)
#define CAPE 8192             // staging slots per bucket / phaseB LDS sort capacity
#define ACH 16384             // edges per partition block
#define GRID_A 428            // ceil(NTOT/ACH)
#define ABLK 1024             // partition block size (16 edges/thread)

struct SpmmJob {
    int mode;           // 0: rating L1, 1: rating L2, 2: social L1, 3: social L2
    int rowBase;
    int nRows;
    const uint2* tblB;  // bf16x4 gather table [*][16]
    const uint2* selfB;
    uint2* outB;
    float4* outF;
    float* wOut;
};

struct CvtJob {
    const float* lo;
    const float* hi;
    uint2* dst;
    int nRows;
    int split;
};

__device__ __forceinline__ int wave_incl_scan(int x) {
    int lane = threadIdx.x & 63;
#pragma unroll
    for (int d = 1; d < 64; d <<= 1) {
        int y = __shfl_up(x, d, 64);
        if (lane >= d) x += y;
    }
    return x;
}

__device__ int block_incl_scan(int x, int* lds) {
    int wid = threadIdx.x >> 6, lane = threadIdx.x & 63;
    int ws_ = wave_incl_scan(x);
    if (lane == 63) lds[wid] = ws_;
    __syncthreads();
    int off = 0;
    for (int w = 0; w < wid; ++w) off += lds[w];
    __syncthreads();
    return ws_ + off;
}

__device__ __forceinline__ float2 unpack_bf16x2(unsigned p) {
    float2 r;
    r.x = __uint_as_float(p << 16);
    r.y = __uint_as_float(p & 0xffff0000u);
    return r;
}

__device__ __forceinline__ unsigned pack_bf16x2(float a, float b) {
    __hip_bfloat162 h = __float22bfloat162_rn(make_float2(a, b));
    return *(unsigned*)&h;
}

__device__ __forceinline__ uint2 pack4(float4 m) {
    return make_uint2(pack_bf16x2(m.x, m.y), pack_bf16x2(m.z, m.w));
}

__device__ __forceinline__ float4 unpack4(uint2 p) {
    float2 a = unpack_bf16x2(p.x), b = unpack_bf16x2(p.y);
    return make_float4(a.x, a.y, b.x, b.y);
}

__device__ __forceinline__ int bid_of(int grow) {
    return (grow < ROW_S0) ? (grow >> 10) : NBR + (grow - ROW_S0) / 384;
}

// f32 table(s) -> bf16x4 table, grid-stride over nRows*16 elements
__device__ __forceinline__ void cvt_body(int blk, int nblks, const CvtJob& cv) {
    int total = cv.nRows * 16;
    int stride = nblks * (int)blockDim.x;
    for (int i = blk * (int)blockDim.x + (int)threadIdx.x; i < total; i += stride) {
        int row = i >> 4, h = i & 15;
        const float* src = (row < cv.split) ? (cv.lo + (size_t)row * DD)
                                            : (cv.hi + (size_t)(row - cv.split) * DD);
        float4 x = *(const float4*)(src + 4 * h);
        cv.dst[i] = pack4(x);
    }
}

// Single-pass staged build with register-cached rows (R12/R13 structure).
__global__ __launch_bounds__(ABLK) void pa_single_kernel(
        const int* __restrict__ rR, const int* __restrict__ rC, const float* __restrict__ rV,
        const int* __restrict__ fR, const int* __restrict__ fC, const float* __restrict__ fV,
        const int* __restrict__ gR, const int* __restrict__ gC, const float* __restrict__ gV,
        int* __restrict__ bucketCur, uint2* __restrict__ ecv) {
    __shared__ int lcnt[NBCK];
    __shared__ int lbase[NBCK];
    int k = blockIdx.x;
    int cbase = k * ACH;
    int eEnd = min(cbase + ACH, NTOT);
    for (int b = threadIdx.x; b < NBCK; b += ABLK) lcnt[b] = 0;
    __syncthreads();
    int gw[16];
#pragma unroll
    for (int t = 0; t < 16; ++t) {
        int e = cbase + t * ABLK + (int)threadIdx.x;
        bool v = e < eEnd;
        int ec = v ? e : cbase;
        int grow;
        if (ec < 5 * NNZC) grow = (ec / NNZC) * NN + rR[ec];
        else if (ec < 6 * NNZC) grow = ROW_S0 + fR[ec - 5 * NNZC];
        else grow = ROW_S0 + UU + gR[ec - 6 * NNZC];
        gw[t] = v ? grow : -1;
    }
#pragma unroll
    for (int t = 0; t < 16; ++t)
        if (gw[t] >= 0) atomicAdd(&lcnt[bid_of(gw[t])], 1);
    __syncthreads();
    for (int b = threadIdx.x; b < NBCK; b += ABLK) {
        int n = lcnt[b];
        lbase[b] = n ? atomicAdd(&bucketCur[b], n) : 0;
    }
    __syncthreads();
    for (int b = threadIdx.x; b < NBCK; b += ABLK) lcnt[b] = 0;
    __syncthreads();
#pragma unroll
    for (int t0 = 0; t0 < 16; t0 += 4) {
        int cc[4]; float vv[4];
#pragma unroll
        for (int u = 0; u < 4; ++u) {
            int t = t0 + u;
            int e = cbase + t * ABLK + (int)threadIdx.x;
            int ec = (gw[t] >= 0) ? e : cbase;
            if (ec < 5 * NNZC) { cc[u] = rC[ec]; vv[u] = rV[ec]; }
            else if (ec < 6 * NNZC) { int kk = ec - 5 * NNZC; cc[u] = fC[kk]; vv[u] = fV[kk]; }
            else { int kk = ec - 6 * NNZC; cc[u] = gC[kk]; vv[u] = gV[kk]; }
        }
        int rk[4], bb[4];
#pragma unroll
        for (int u = 0; u < 4; ++u) {
            int t = t0 + u;
            bb[u] = (gw[t] >= 0) ? bid_of(gw[t]) : 0;
            rk[u] = (gw[t] >= 0) ? atomicAdd(&lcnt[bb[u]], 1) : CAPE;
        }
#pragma unroll
        for (int u = 0; u < 4; ++u) {
            int t = t0 + u;
            if (gw[t] < 0) continue;
            int off = lbase[bb[u]] + rk[u];
            if (off >= CAPE) continue;
            int lrow = (gw[t] < ROW_S0) ? (gw[t] & 1023) : ((gw[t] - ROW_S0) % 384);
            ecv[(size_t)bb[u] * CAPE + off] =
                make_uint2(((unsigned)lrow << 18) | (unsigned)cc[u], __float_as_uint(vv[u]));
        }
    }
}

// block 0: exclusive scan -> bStart + sentinels; blocks [1,1+cvB): cvt; block 1+cvB: att_vec
__global__ __launch_bounds__(256) void bscan_kernel(const int* __restrict__ bucketCur,
                                                    int* __restrict__ bStart,
                                                    int* __restrict__ rowptr,
                                                    CvtJob cv, int cvB,
                                                    const float* __restrict__ au,
                                                    const float* __restrict__ Mu,
                                                    const float* __restrict__ ai,
                                                    const float* __restrict__ Mi,
                                                    const float* __restrict__ as_,
                                                    const float* __restrict__ Ms,
                                                    float* __restrict__ vvec) {
    if ((int)blockIdx.x == 1 + cvB) {
        int d = threadIdx.x;
        if (d < DD) {
            float su = 0.f, si = 0.f, ss = 0.f;
            for (int e = 0; e < DD; ++e) {
                su += au[e] * Mu[e * DD + d];
                si += ai[e] * Mi[e * DD + d];
                ss += as_[e] * Ms[e * DD + d];
            }
            vvec[d] = su;
            vvec[DD + d] = si;
            vvec[2 * DD + d] = ss;
        }
        return;
    }
    if (blockIdx.x > 0) {
        cvt_body(blockIdx.x - 1, cvB, cv);
        return;
    }
    __shared__ int lds8[8];
    __shared__ int sOff;
    if (threadIdx.x == 0) sOff = 0;
    __syncthreads();
    for (int base = 0; base < NBCK; base += 256) {
        int i = base + threadIdx.x;
        int v = (i < NBCK) ? min(bucketCur[i], CAPE) : 0;
        int incl = block_incl_scan(v, lds8);
        if (i < NBCK) bStart[i] = sOff + incl - v;
        __syncthreads();
        if (threadIdx.x == 255) sOff += incl;
        __syncthreads();
    }
    if (threadIdx.x == 0) { bStart[NBCK] = sOff; rowptr[MTOT] = sOff; }
}

// per-bucket LDS permutation sort (+ folded cvt tail)
__global__ __launch_bounds__(256) void phaseB_kernel(const int* __restrict__ bStart,
                                                     const int* __restrict__ bucketCur,
                                                     int* __restrict__ rowptr,
                                                     const uint2* __restrict__ ecv,
                                                     uint2* __restrict__ edata,
                                                     CvtJob cv, int cvB) {
    if ((int)blockIdx.x >= NBCK) {
        cvt_body(blockIdx.x - NBCK, cvB, cv);
        return;
    }
    __shared__ unsigned short perm[CAPE];  // 16 KB
    __shared__ int off[1024];
    __shared__ int lds8[8];
    int b = blockIdx.x;
    int firstRow = (b < NBR) ? (b << 10) : ROW_S0 + (b - NBR) * 384;
    int rowEnd = (b < NBR) ? min((b + 1) << 10, ROW_S0)
                           : min(ROW_S0 + (b - NBR + 1) * 384, MTOT);
    int nRows = rowEnd - firstRow;
    size_t src = (size_t)b * CAPE;
    int dst = bStart[b];
    int count = min(bucketCur[b], CAPE);
    for (int i = threadIdx.x; i < nRows; i += 256) off[i] = 0;
    __syncthreads();
    for (int i = threadIdx.x; i < count; i += 256)
        atomicAdd(&off[ecv[src + i].x >> 18], 1);
    __syncthreads();
    int base4 = threadIdx.x * 4;
    int v4[4], s = 0;
#pragma unroll
    for (int kk = 0; kk < 4; ++kk) {
        int i = base4 + kk;
        v4[kk] = (i < nRows) ? off[i] : 0;
        s += v4[kk];
    }
    int incl = block_incl_scan(s, lds8);
    int run = incl - s;
#pragma unroll
    for (int kk = 0; kk < 4; ++kk) {
        int i = base4 + kk;
        if (i < nRows) { rowptr[firstRow + i] = dst + run; off[i] = run; }
        run += v4[kk];
    }
    __syncthreads();
    for (int i = threadIdx.x; i < count; i += 256) {
        int pos = atomicAdd(&off[ecv[src + i].x >> 18], 1);
        perm[pos] = (unsigned short)i;
    }
    __syncthreads();
    for (int i = threadIdx.x; i < count; i += 256) {
        uint2 e = ecv[src + perm[i]];
        edata[dst + i] = make_uint2(e.x & 0x3FFFFu, e.y);
    }
}

// 16 lanes/row, 4 rows/wave, 8-edge MLP batches; ALL gathers bf16x4 from tblB.
template <int MODE>
__device__ __forceinline__ void spmm_body(int blk, const SpmmJob& j,
                                          const int* __restrict__ rowptr,
                                          const uint2* __restrict__ edata,
                                          const float* __restrict__ vvec) {
    int lane = threadIdx.x & 63;
    int l16 = lane & 15;
    int grpBase = lane & 48;
    int wid = blk * (int)(blockDim.x >> 6) + (threadIdx.x >> 6);
    int row = wid * 4 + (lane >> 4);
    bool active = row < j.nRows;
    int g = j.rowBase + row;
    int start = active ? rowptr[g] : 0;
    int end = active ? rowptr[g + 1] : 0;
    float4 acc = make_float4(0.f, 0.f, 0.f, 0.f);
    for (int j0 = start; j0 < end; j0 += 16) {
        uint2 md = make_uint2(0u, 0u);
        if (j0 + l16 < end) md = edata[j0 + l16];
        int cnt = min(end - j0, 16);
        for (int js = 0; js < cnt; js += 8) {
            int cc[8]; float vv[8]; float4 xv[8];
#pragma unroll
            for (int u = 0; u < 8; ++u) {
                int jj = js + u;
                int sl = grpBase + ((jj < cnt) ? jj : 0);
                cc[u] = __shfl((int)md.x, sl, 64);
                float v = __uint_as_float((unsigned)__shfl((int)md.y, sl, 64));
                vv[u] = (jj < cnt) ? v : 0.f;
            }
#pragma unroll
            for (int u = 0; u < 8; ++u)
                xv[u] = unpack4(j.tblB[(size_t)cc[u] * 16 + l16]);
#pragma unroll
            for (int u = 0; u < 8; ++u) {
                acc.x += vv[u] * xv[u].x; acc.y += vv[u] * xv[u].y;
                acc.z += vv[u] * xv[u].z; acc.w += vv[u] * xv[u].w;
            }
        }
    }
    if (!active) return;
    size_t ro = (size_t)row * 16 + l16;
    if (MODE == 0) {
        j.outB[ro] = pack4(acc);
    } else if (MODE == 1) {
        float4 sv = unpack4(j.selfB[ro]);
        float4 m = make_float4(0.5f * (acc.x + sv.x), 0.5f * (acc.y + sv.y),
                               0.5f * (acc.z + sv.z), 0.5f * (acc.w + sv.w));
        j.outB[ro] = pack4(m);
        const float* vv = (row < UU) ? vvec : (vvec + DD);
        float4 vw = *(const float4*)(vv + 4 * l16);
        float p = m.x * vw.x + m.y * vw.y + m.z * vw.z + m.w * vw.w;
        p += __shfl_xor(p, 1, 64); p += __shfl_xor(p, 2, 64);
        p += __shfl_xor(p, 4, 64); p += __shfl_xor(p, 8, 64);
        if (l16 == 0) j.wOut[row] = tanhf(p);
    } else if (MODE == 2) {
        float n2 = acc.x * acc.x + acc.y * acc.y + acc.z * acc.z + acc.w * acc.w;
        n2 += __shfl_xor(n2, 1, 64); n2 += __shfl_xor(n2, 2, 64);
        n2 += __shfl_xor(n2, 4, 64); n2 += __shfl_xor(n2, 8, 64);
        float inv = 1.f / fmaxf(sqrtf(n2), 1e-12f);
        j.outB[ro] = pack4(make_float4(acc.x * inv, acc.y * inv, acc.z * inv, acc.w * inv));
    } else {
        float n2 = acc.x * acc.x + acc.y * acc.y + acc.z * acc.z + acc.w * acc.w;
        n2 += __shfl_xor(n2, 1, 64); n2 += __shfl_xor(n2, 2, 64);
        n2 += __shfl_xor(n2, 4, 64); n2 += __shfl_xor(n2, 8, 64);
        float inv = 1.f / fmaxf(sqrtf(n2), 1e-12f);
        float4 sv = unpack4(j.selfB[ro]);
        j.outF[ro] = make_float4(0.5f * (sv.x + acc.x * inv), 0.5f * (sv.y + acc.y * inv),
                                 0.5f * (sv.z + acc.z * inv), 0.5f * (sv.w + acc.w * inv));
    }
}

__device__ __forceinline__ void spmm_run(const SpmmJob& j, int blk,
                                         const int* __restrict__ rowptr,
                                         const uint2* __restrict__ edata,
                                         const float* __restrict__ vvec) {
    switch (j.mode) {
        case 0: spmm_body<0>(blk, j, rowptr, edata, vvec); break;
        case 1: spmm_body<1>(blk, j, rowptr, edata, vvec); break;
        case 2: spmm_body<2>(blk, j, rowptr, edata, vvec); break;
        default: spmm_body<3>(blk, j, rowptr, edata, vvec); break;
    }
}

// up to two spmm jobs + folded cvt tail
__global__ __launch_bounds__(256) void fused_kernel(SpmmJob a, int aB, SpmmJob b, int bB,
                                                    CvtJob cv, int cvB,
                                                    const int* __restrict__ rowptr,
                                                    const uint2* __restrict__ edata,
                                                    const float* __restrict__ vvec) {
    int bx = blockIdx.x;
    if (bx < aB) { spmm_run(a, bx, rowptr, edata, vvec); return; }
    bx -= aB;
    if (bx < bB) { spmm_run(b, bx, rowptr, edata, vvec); return; }
    cvt_body(bx - bB, cvB, cv);
}

// blocks [0,nMix): vectorized 5-channel softmax mix (16 lanes/row, 4 rows/wave,
// bf16x4 loads); then two social-L1 spmm jobs
__global__ __launch_bounds__(256) void mix_social_kernel(
        const uint2* __restrict__ chanEmbU2, const float* __restrict__ w,
        float* __restrict__ oUS, float* __restrict__ oIS,
        float* __restrict__ mixedRU, float* __restrict__ oMI, int nMix,
        SpmmJob s0, int s0B, SpmmJob s1,
        const int* __restrict__ rowptr, const uint2* __restrict__ edata,
        const float* __restrict__ vvec) {
    if ((int)blockIdx.x >= nMix) {
        int r = blockIdx.x - nMix;
        if (r < s0B) spmm_body<2>(r, s0, rowptr, edata, vvec);
        else spmm_body<2>(r - s0B, s1, rowptr, edata, vvec);
        return;
    }
    int lane = threadIdx.x & 63;
    int l16 = lane & 15;
    int wid = blockIdx.x * 4 + (threadIdx.x >> 6);
    int n = wid * 4 + (lane >> 4);
    if (n >= NN) return;
    float sw[5];
    float mx = -2.0f;
#pragma unroll
    for (int c = 0; c < 5; ++c) {
        sw[c] = w[(size_t)c * NN + n];
        mx = fmaxf(mx, sw[c]);
    }
    float sum = 0.f;
#pragma unroll
    for (int c = 0; c < 5; ++c) {
        sw[c] = __expf(sw[c] - mx);
        sum += sw[c];
    }
    float inv = 1.0f / sum;
#pragma unroll
    for (int c = 0; c < 5; ++c) sw[c] *= inv;
    float4 acc = make_float4(0.f, 0.f, 0.f, 0.f);
#pragma unroll
    for (int c = 0; c < 5; ++c) {
        float4 xv = unpack4(chanEmbU2[((size_t)c * NN + n) * 16 + l16]);
        acc.x += sw[c] * xv.x; acc.y += sw[c] * xv.y;
        acc.z += sw[c] * xv.z; acc.w += sw[c] * xv.w;
    }
    if (n < UU) {
        if (l16 < 5) oUS[(size_t)l16 * UU + n] = sw[l16];
        *(float4*)(mixedRU + (size_t)n * DD + 4 * l16) = acc;
    } else {
        int m = n - UU;
        if (l16 < 5) oIS[(size_t)l16 * II + m] = sw[l16];
        *(float4*)(oMI + (size_t)m * DD + 4 * l16) = acc;
    }
}

// social 2-channel softmax fuse + adaptive final combine
__global__ void social_mix_final_kernel(const float* __restrict__ e0, const float* __restrict__ e1,
                                        const float* __restrict__ vs,
                                        const float* __restrict__ mixedRU,
                                        const float* __restrict__ adaptive,
                                        float* __restrict__ scoresOut,
                                        float* __restrict__ outMU) {
    int lane = threadIdx.x & 63;
    int n = blockIdx.x * (blockDim.x >> 6) + (threadIdx.x >> 6);
    if (n >= UU) return;
    size_t idx = (size_t)n * DD + lane;
    float a = e0[idx];
    float b = e1[idx];
    float v = vs[lane];
    float pa = a * v, pb = b * v;
    float mru = mixedRU[idx];
#pragma unroll
    for (int m = 32; m >= 1; m >>= 1) { pa += __shfl_xor(pa, m, 64); pb += __shfl_xor(pb, m, 64); }
    float w0 = tanhf(pa);
    float w1 = tanhf(pb);
    float mx = fmaxf(w0, w1);
    float x0 = __expf(w0 - mx);
    float x1 = __expf(w1 - mx);
    float invs = 1.0f / (x0 + x1);
    float s0 = x0 * invs;
    float s1 = x1 * invs;
    if (lane == 0) {
        scoresOut[n] = s0;
        scoresOut[UU + n] = s1;
    }
    float ms = s0 * a + s1 * b;
    float nm = mru * ms, na2 = mru * mru, nb2 = ms * ms;
#pragma unroll
    for (int m = 32; m >= 1; m >>= 1) {
        nm += __shfl_xor(nm, m, 64); na2 += __shfl_xor(na2, m, 64); nb2 += __shfl_xor(nb2, m, 64);
    }
    float denom = fmaxf(sqrtf(na2), 1e-8f) * fmaxf(sqrtf(nb2), 1e-8f);
    float sim = nm / denom;
    float rate = 1.0f / (2.0f + fmaxf(sim, 0.f) * adaptive[n]);
    outMU[idx] = mru + ms * rate;
}

extern "C" void kernel_launch(void* const* d_in, const int* in_sizes, int n_in,
                              void* d_out, int out_size, void* d_ws, size_t ws_size,
                              hipStream_t stream) {
    const int* r_rows = (const int*)d_in[0];
    const int* r_cols = (const int*)d_in[1];
    const float* r_vals = (const float*)d_in[2];
    const int* f_rows = (const int*)d_in[3];
    const int* f_cols = (const int*)d_in[4];
    const float* f_vals = (const float*)d_in[5];
    const int* g_rows = (const int*)d_in[6];
    const int* g_cols = (const int*)d_in[7];
    const float* g_vals = (const float*)d_in[8];
    const float* rue = (const float*)d_in[9];
    const float* rie = (const float*)d_in[10];
    const float* femb = (const float*)d_in[11];
    const float* gemb = (const float*)d_in[12];
    const float* uaw = (const float*)d_in[13];
    const float* uamw = (const float*)d_in[14];
    const float* iaw = (const float*)d_in[15];
    const float* iamw = (const float*)d_in[16];
    const float* saw = (const float*)d_in[17];
    const float* samw = (const float*)d_in[18];
    const float* adapt = (const float*)d_in[19];

    // ws layout (float units) — total 55,944,320 floats = 223.8 MB
    float* ws = (float*)d_ws;
    int* rowptr = (int*)ws;                              // 870,016
    int* bStart = rowptr + 870016;                       // 2,048
    int* bucketCur = bStart + 2048;                      // 2,048 -> meta ends @874,112
    float* ED   = ws + 874112;                           // 14,000,000 (edata)
    float* R1   = ED + 14000000;                         // 11,520,000
    float* CM   = R1 + 11520000;                         // 24,000,000
    float* tbl0F= CM + 24000000;                         // 4,800,000
    float* wrat = tbl0F + 4800000;                       // 750,016
    float* vvec = wrat + 750016;                         // 192

    uint2* edata = (uint2*)ED;
    uint2* AtmpB0 = (uint2*)R1;                          // NN*16 uint2
    uint2* AtmpB1 = AtmpB0 + (size_t)NN * 16;
    float* mixedRU = R1;                                 // UU*64 f32 (after rating)
    float* socM0 = R1 + 3840000;
    float* socM1 = R1 + 7680000;
    uint2* ecv = (uint2*)CM;
    __hip_bfloat16* chanMean = (__hip_bfloat16*)CM;      // 5*NN*64 bf16
    uint2* tbl1 = (uint2*)(CM + 19200000);               // chanMean slice-4 space
    uint2* tbl0 = (uint2*)tbl0F;
    uint2* socB0 = (uint2*)tbl0F;                        // UU*16 uint2
    uint2* socB1 = socB0 + (size_t)UU * 16;

    float* out = (float*)d_out;
    float* oUS = out;
    float* oIS = oUS + (size_t)5 * UU;
    float* oSS = oIS + (size_t)5 * II;
    float* oMU = oSS + (size_t)2 * UU;
    float* oMI = oMU + (size_t)UU * DD;
    uint2* socL1B0 = (uint2*)oMU;                        // scratch in dead oMU region
    uint2* socL1B1 = socL1B0 + (size_t)UU * 16;

    const dim3 blk(256);
    const dim3 blkA(ABLK);
    const int gridN4 = (NN + 15) / 16;    // 9375
    const int gridU4 = (UU + 15) / 16;    // 3750
    const int gridMix4 = (NN + 15) / 16;  // 9375 (4 rows/wave now)
    const int gridFin = (UU + 3) / 4;
    const int CVB = 2048;

    uint2* tblOf[2] = {tbl0, tbl1};
    auto cvtRating = [&](int c) {
        CvtJob cv{};
        cv.lo = rue + (size_t)c * UU * DD;
        cv.hi = rie + (size_t)c * II * DD;
        cv.dst = tblOf[c & 1];
        cv.nRows = NN; cv.split = UU;
        return cv;
    };
    CvtJob cvNone{};
    cvNone.lo = rue; cvNone.hi = rie; cvNone.dst = tbl0; cvNone.nRows = 0; cvNone.split = UU;

    // ---- build row-sorted CSR: single-pass staged scatter ----
    hipMemsetAsync(bucketCur, 0, NBCK * sizeof(int), stream);
    pa_single_kernel<<<GRID_A, blkA, 0, stream>>>(r_rows, r_cols, r_vals,
                                                  f_rows, f_cols, f_vals,
                                                  g_rows, g_cols, g_vals,
                                                  bucketCur, ecv);
    bscan_kernel<<<2 + CVB, blk, 0, stream>>>(bucketCur, bStart, rowptr,
                                              cvtRating(0), CVB,
                                              uaw, uamw, iaw, iamw, saw, samw, vvec);
    phaseB_kernel<<<NBCK + CVB, blk, 0, stream>>>(bStart, bucketCur, rowptr, ecv, edata,
                                                  cvtRating(1), CVB);

    // ---- rating channels: L1(c) || L2(c-1), cvt(c+1) folded ----
    auto jobL1 = [&](int c) {
        SpmmJob j{};
        j.mode = 0; j.rowBase = c * NN; j.nRows = NN;
        j.tblB = tblOf[c & 1];
        j.outB = (c & 1) ? AtmpB1 : AtmpB0;
        return j;
    };
    auto jobL2 = [&](int c) {
        SpmmJob j{};
        j.mode = 1; j.rowBase = c * NN; j.nRows = NN;
        j.tblB = (c & 1) ? AtmpB1 : AtmpB0;
        j.selfB = j.tblB;
        j.outB = (uint2*)(chanMean + (size_t)c * NN * DD);
        j.wOut = wrat + (size_t)c * NN;
        return j;
    };
    SpmmJob jNone{}; jNone.mode = 0; jNone.nRows = 0; jNone.tblB = tbl0; jNone.outB = AtmpB0;

    fused_kernel<<<gridN4, blk, 0, stream>>>(jobL1(0), gridN4, jNone, 0, cvNone, 0,
                                             rowptr, edata, vvec);
    for (int c = 1; c <= 3; ++c)
        fused_kernel<<<2 * gridN4 + CVB, blk, 0, stream>>>(
            jobL1(c), gridN4, jobL2(c - 1), gridN4, cvtRating(c + 1), CVB,
            rowptr, edata, vvec);
    fused_kernel<<<2 * gridN4, blk, 0, stream>>>(jobL1(4), gridN4, jobL2(3), gridN4,
                                                 cvNone, 0, rowptr, edata, vvec);
    CvtJob cvSoc{};
    cvSoc.lo = femb; cvSoc.hi = gemb; cvSoc.dst = socB0; cvSoc.nRows = 2 * UU; cvSoc.split = UU;
    fused_kernel<<<gridN4 + CVB, blk, 0, stream>>>(jobL2(4), gridN4, jNone, 0, cvSoc, CVB,
                                                   rowptr, edata, vvec);

    // ---- attention fuse (vectorized) || social L1 ----
    SpmmJob sf1{}; sf1.mode = 2; sf1.rowBase = ROW_S0; sf1.nRows = UU;
    sf1.tblB = socB0; sf1.outB = socL1B0;
    SpmmJob sg1{}; sg1.mode = 2; sg1.rowBase = ROW_S0 + UU; sg1.nRows = UU;
    sg1.tblB = socB1; sg1.outB = socL1B1;
    mix_social_kernel<<<gridMix4 + 2 * gridU4, blk, 0, stream>>>(
        (const uint2*)chanMean, wrat, oUS, oIS, mixedRU, oMI, gridMix4,
        sf1, gridU4, sg1, rowptr, edata, vvec);

    // ---- social L2 ----
    SpmmJob sf2{}; sf2.mode = 3; sf2.rowBase = ROW_S0; sf2.nRows = UU;
    sf2.tblB = socL1B0; sf2.selfB = socL1B0; sf2.outF = (float4*)socM0;
    SpmmJob sg2{}; sg2.mode = 3; sg2.rowBase = ROW_S0 + UU; sg2.nRows = UU;
    sg2.tblB = socL1B1; sg2.selfB = socL1B1; sg2.outF = (float4*)socM1;
    fused_kernel<<<2 * gridU4, blk, 0, stream>>>(sf2, gridU4, sg2, gridU4, cvNone, 0,
                                                 rowptr, edata, vvec);

    // ---- social fuse + adaptive combine ----
    social_mix_final_kernel<<<gridFin, blk, 0, stream>>>(socM0, socM1, vvec + 2 * DD,
                                                         mixedRU, adapt, oSS, oMU);
}